// Round 12
// baseline (259.168 us; speedup 1.0000x reference)
//
#include <hip/hip_runtime.h>
#include <hip/hip_bf16.h>

#define N_NODES 50000
#define N_EDGES 800000
#define FDIM 128
#define CDIM 64
#define NGRAPH 256
#define LRELU_SLOPE 0.2f
#define NBUCK ((N_NODES + 255) / 256)       // 196 buckets of 256 nodes
#define BCAP 5120                            // stage capacity/bucket
#define ABLK 400                             // pass-A blocks
#define EPB ((N_EDGES + ABLK - 1) / ABLK)    // 2000 edges per pass-A block
#define NDBIN 64                             // degree bins for per-bucket ordering
#define GEMMB ((N_NODES + 63) / 64)          // 782 row-tiles

typedef unsigned short ushort_t;
typedef unsigned int uint_t;
typedef __attribute__((ext_vector_type(8))) short short8v;
typedef __attribute__((ext_vector_type(4))) float float4v;

// ---------------------------------------------------------------- bf16 helpers (RNE)
__device__ __forceinline__ ushort_t f2bf(float f) {
    uint_t u = __float_as_uint(f);
    u += 0x7FFFu + ((u >> 16) & 1u);
    return (ushort_t)(u >> 16);
}
__device__ __forceinline__ float bf2f(ushort_t u) {
    return __uint_as_float(((uint_t)u) << 16);
}

__device__ __forceinline__ float fast_exp2(float x) {
    return __builtin_amdgcn_exp2f(x);
}

__device__ __forceinline__ int wave_incl_scan(int v, int lane) {
#pragma unroll
    for (int off = 1; off < 64; off <<= 1) {
        int t = __shfl_up(v, off);
        if (lane >= off) v += t;
    }
    return v;
}

__device__ __forceinline__ float wave_sum(float v) {
#pragma unroll
    for (int off = 32; off >= 1; off >>= 1) v += __shfl_xor(v, off);
    return v;
}

// ---------------------------------------------------------------- x fp32 -> bf16
__global__ void k_cvt_x(const float* __restrict__ x, ushort_t* __restrict__ xb) {
    int i = blockIdx.x * 256 + threadIdx.x;
    const int TOT = N_NODES * FDIM / 8;
    if (i >= TOT) return;
    const float* p = x + (size_t)i * 8;
    float4 a = *reinterpret_cast<const float4*>(p);
    float4 b = *reinterpret_cast<const float4*>(p + 4);
    short8v o;
    o[0] = (short)f2bf(a.x); o[1] = (short)f2bf(a.y);
    o[2] = (short)f2bf(a.z); o[3] = (short)f2bf(a.w);
    o[4] = (short)f2bf(b.x); o[5] = (short)f2bf(b.y);
    o[6] = (short)f2bf(b.z); o[7] = (short)f2bf(b.w);
    *reinterpret_cast<short8v*>(xb + (size_t)i * 8) = o;
}

// ---------------------------------------------------------------- CSR build
// pass A: bucket edges by dst>>8 (edges kept in registers across both phases)
__global__ void k_bucket(const int* __restrict__ src, const int* __restrict__ dst,
                         int* __restrict__ bcnt, int2* __restrict__ stage) {
    __shared__ int lhist[NBUCK];
    __shared__ int lbase[NBUCK];
    __shared__ int lcur[NBUCK];
    int tid = threadIdx.x;
    int e0 = blockIdx.x * EPB;
    int e1 = min(e0 + EPB, N_EDGES);
    int es[8], ed[8];
    int myn = 0;
#pragma unroll
    for (int k = 0; k < 8; k++) {
        int e = e0 + tid + k * 256;
        if (e < e1) { es[k] = src[e]; ed[k] = dst[e]; myn = k + 1; }
    }
    for (int t = tid; t < NBUCK; t += 256) { lhist[t] = 0; lcur[t] = 0; }
    __syncthreads();
#pragma unroll
    for (int k = 0; k < 8; k++)
        if (k < myn) atomicAdd(&lhist[ed[k] >> 8], 1);
    __syncthreads();
    for (int t = tid; t < NBUCK; t += 256)
        lbase[t] = lhist[t] ? atomicAdd(&bcnt[t], lhist[t]) : 0;
    __syncthreads();
#pragma unroll
    for (int k = 0; k < 8; k++) {
        if (k < myn) {
            int b = ed[k] >> 8;
            int loff = atomicAdd(&lcur[b], 1);
            int pos = lbase[b] + loff;
            if (pos < BCAP) stage[(size_t)b * BCAP + pos] = make_int2(es[k], ed[k]);
        }
    }
}

// exclusive scan of bucket counts (one block) + zero the pool buffer g
__global__ void k_bscan(const int* __restrict__ bcnt, int* __restrict__ bbase,
                        float4* __restrict__ g4) {
    __shared__ int wsum[4];
    int tid = threadIdx.x;
    int lane = tid & 63, w = tid >> 6;
    int v = (tid < NBUCK) ? bcnt[tid] : 0;
    int incl = wave_incl_scan(v, lane);
    if (lane == 63) wsum[w] = incl;
    __syncthreads();
    if (tid == 0) {
        int s = 0;
#pragma unroll
        for (int k = 0; k < 4; k++) { int t = wsum[k]; wsum[k] = s; s += t; }
    }
    __syncthreads();
    if (tid < NBUCK) bbase[tid] = incl - v + wsum[w];
    const int G4 = NGRAPH * 64 / 4;
    for (int i = tid; i < G4; i += 256) g4[i] = make_float4(0.f, 0.f, 0.f, 0.f);
}

// fused per-bucket: node hist + rowptr + per-bucket degree-sort order + scatter
__global__ void k_csr(const int* __restrict__ bcnt, const int* __restrict__ bbase,
                      const int2* __restrict__ stage, int* __restrict__ rowptr,
                      int* __restrict__ order, int* __restrict__ csr_src) {
    __shared__ int lcnt[256];
    __shared__ int lcur[256];
    __shared__ int dh[NDBIN];
    __shared__ int dbase[NDBIN];
    __shared__ int wsum[4];
    int b = blockIdx.x;
    int tid = threadIdx.x;
    int lane = tid & 63, w = tid >> 6;
    lcnt[tid] = 0;
    if (tid < NDBIN) dh[tid] = 0;
    __syncthreads();
    int n = min(bcnt[b], BCAP);
    const int2* sp = stage + (size_t)b * BCAP;
    for (int i = tid; i < n; i += 256)
        atomicAdd(&lcnt[sp[i].y & 255], 1);
    __syncthreads();
    int v = lcnt[tid];
    int incl = wave_incl_scan(v, lane);
    if (lane == 63) wsum[w] = incl;
    __syncthreads();
    if (tid == 0) {
        int s = 0;
#pragma unroll
        for (int k = 0; k < 4; k++) { int t = wsum[k]; wsum[k] = s; s += t; }
    }
    __syncthreads();
    int excl = incl - v + wsum[w];
    int bb = bbase[b];
    int node = (b << 8) + tid;
    bool okn = node < N_NODES;
    int dg = min(v, NDBIN - 1);
    if (okn) {
        rowptr[node] = bb + excl;
        atomicAdd(&dh[dg], 1);
    }
    lcur[tid] = excl;
    if (b == 0 && tid == 0) rowptr[N_NODES] = N_EDGES;
    __syncthreads();
    if (tid < NDBIN) {
        int dv = dh[tid];
        int din = wave_incl_scan(dv, tid);   // lanes 0..63 of wave 0
        dbase[tid] = din - dv;
    }
    __syncthreads();
    if (okn) {
        int r = atomicAdd(&dbase[dg], 1);    // per-bucket compact rank
        order[(b << 8) + r] = node;
    }
    for (int i = tid; i < n; i += 256) {
        int2 sd = sp[i];
        int pos = atomicAdd(&lcur[sd.y & 255], 1);
        csr_src[bb + pos] = sd.x;
    }
}

// ---------------------------------------------------------------- weight f32 -> hi/lo bf16
struct WSrc {
    const float* s[7];
    int off[8];
};
__global__ void k_cvt_w(WSrc ws, ushort_t* __restrict__ hi, ushort_t* __restrict__ lo) {
    int gid = blockIdx.x * 256 + threadIdx.x;
    int stride = gridDim.x * 256;
#pragma unroll
    for (int mi = 0; mi < 7; mi++) {
        int n = ws.off[mi + 1] - ws.off[mi];
        const float* s = ws.s[mi];
        ushort_t* h = hi + ws.off[mi];
        ushort_t* l = lo + ws.off[mi];
        for (int i = gid; i < n; i += stride) {
            float f = s[i];
            ushort_t hb = f2bf(f);
            h[i] = hb;
            l[i] = f2bf(f - bf2f(hb));
        }
    }
}

// ---------------------------------------------------------------- projection via MFMA
template <int K>
__global__ void k_gemm_dual_mfma(const ushort_t* __restrict__ xa,
                                 const ushort_t* __restrict__ wlh, const ushort_t* __restrict__ wll,
                                 const ushort_t* __restrict__ wrh, const ushort_t* __restrict__ wrl,
                                 const float* __restrict__ bl, const float* __restrict__ br,
                                 ushort_t* __restrict__ xl, ushort_t* __restrict__ xr) {
    int tid = threadIdx.x;
    int wv = tid >> 6, lane = tid & 63;
    bool rhalf = blockIdx.x >= GEMMB;
    int blk = rhalf ? blockIdx.x - GEMMB : blockIdx.x;
    int m0 = blk * 64 + wv * 16;
    if (m0 >= N_NODES) return;
    int arow = min(m0 + (lane & 15), N_NODES - 1);
    int koff = (lane >> 4) * 8;
    int wrow = lane & 15;
    const ushort_t* bh  = rhalf ? wrh : wlh;
    const ushort_t* blo = rhalf ? wrl : wll;
    const float* bias   = rhalf ? br : bl;
    ushort_t* outp      = rhalf ? xr : xl;

    short8v afrag[K / 32];
#pragma unroll
    for (int kk = 0; kk < K / 32; kk++)
        afrag[kk] = *reinterpret_cast<const short8v*>(xa + (size_t)arow * K + kk * 32 + koff);

    float4v acc[4];
#pragma unroll
    for (int f = 0; f < 4; f++) acc[f] = (float4v)(0.f);

#pragma unroll
    for (int kk = 0; kk < K / 32; kk++) {
#pragma unroll
        for (int f = 0; f < 4; f++) {
            size_t boff = (size_t)(f * 16 + wrow) * K + kk * 32 + koff;
            short8v bfh = *reinterpret_cast<const short8v*>(bh + boff);
            short8v bfl = *reinterpret_cast<const short8v*>(blo + boff);
            acc[f] = __builtin_amdgcn_mfma_f32_16x16x32_bf16(afrag[kk], bfh, acc[f], 0, 0, 0);
            acc[f] = __builtin_amdgcn_mfma_f32_16x16x32_bf16(afrag[kk], bfl, acc[f], 0, 0, 0);
        }
    }

    int r0 = m0 + (lane >> 4) * 4;
#pragma unroll
    for (int f = 0; f < 4; f++) {
        int col = f * 16 + (lane & 15);
        float bv = bias[col];
#pragma unroll
        for (int j = 0; j < 4; j++) {
            int row = r0 + j;
            if (row < N_NODES) outp[(size_t)row * 64 + col] = f2bf(acc[f][j] + bv);
        }
    }
}

// ---------------------------------------------------------------- fused: h = relu(concat@W.T+b) -> global_add_pool
__global__ void k_gemm_h_pool(const ushort_t* __restrict__ x1, const ushort_t* __restrict__ x2,
                              const ushort_t* __restrict__ x3,
                              const ushort_t* __restrict__ whi, const ushort_t* __restrict__ wlo,
                              const float* __restrict__ b, const int* __restrict__ batch,
                              float* __restrict__ g) {
    __shared__ float ht[64][65];
    int tid = threadIdx.x;
    int wv = tid >> 6, lane = tid & 63;
    int m0 = blockIdx.x * 64 + wv * 16;
    bool wactive = m0 < N_NODES;

    if (wactive) {
        int arow = min(m0 + (lane & 15), N_NODES - 1);
        int koff = (lane >> 4) * 8;
        int wrow = lane & 15;
        float4v acc[4];
#pragma unroll
        for (int f = 0; f < 4; f++) acc[f] = (float4v)(0.f);
#pragma unroll
        for (int ks = 0; ks < 6; ks++) {
            int k0 = ks * 32;
            const ushort_t* srcp = (ks < 2) ? x1 : (ks < 4 ? x2 : x3);
            int kc = k0 & 63;
            short8v afrag = *reinterpret_cast<const short8v*>(srcp + (size_t)arow * 64 + kc + koff);
#pragma unroll
            for (int f = 0; f < 4; f++) {
                size_t boff = (size_t)(f * 16 + wrow) * 192 + k0 + koff;
                short8v bfh = *reinterpret_cast<const short8v*>(whi + boff);
                short8v bfl = *reinterpret_cast<const short8v*>(wlo + boff);
                acc[f] = __builtin_amdgcn_mfma_f32_16x16x32_bf16(afrag, bfh, acc[f], 0, 0, 0);
                acc[f] = __builtin_amdgcn_mfma_f32_16x16x32_bf16(afrag, bfl, acc[f], 0, 0, 0);
            }
        }
        int r0 = wv * 16 + (lane >> 4) * 4;
#pragma unroll
        for (int f = 0; f < 4; f++) {
            int col = f * 16 + (lane & 15);
            float bias = b[col];
#pragma unroll
            for (int j = 0; j < 4; j++) {
                float o = acc[f][j] + bias;
                ht[r0 + j][col] = o > 0.f ? o : 0.f;
            }
        }
    }
    __syncthreads();

    int c = tid & 63, rr = tid >> 6;
    int blkbase = blockIdx.x * 64;
    float acc = 0.f;
    int cur = -1;
    for (int r = rr; r < 64; r += 4) {
        int node = blkbase + r;
        if (node >= N_NODES) break;
        int bb = batch[node];
        if (bb != cur) {
            if (cur >= 0) atomicAdd(&g[cur * 64 + c], acc);
            cur = bb;
            acc = 0.f;
        }
        acc += ht[r][c];
    }
    if (cur >= 0) atomicAdd(&g[cur * 64 + c], acc);
}

// ---------------------------------------------------------------- GATv2 aggregate
// 4 nodes/wave (16 lanes, 4ch/lane); 16-edge iterations; index prefetch one iter ahead
__global__ void k_gat(const ushort_t* __restrict__ xl, const ushort_t* __restrict__ xr,
                      const int* __restrict__ rowptr, const int* __restrict__ csr_src,
                      const int* __restrict__ order,
                      const float* __restrict__ att, const float* __restrict__ bo,
                      ushort_t* __restrict__ xout) {
    int tid = threadIdx.x;
    int wv = tid >> 6, lane = tid & 63;
    int gl = lane & 15;
    int slot = blockIdx.x * 16 + wv * 4 + (lane >> 4);
    if (slot >= N_NODES) return;
    int node = order[slot];
    const float LOG2E = 1.44269504f;
    int c0 = gl * 4;
    float4 a4 = *reinterpret_cast<const float4*>(att + c0);
    float at0 = a4.x * LOG2E, at1 = a4.y * LOG2E, at2 = a4.z * LOG2E, at3 = a4.w * LOG2E;
    size_t nb = (size_t)node * 64 + c0;
    ushort4 qr = *reinterpret_cast<const ushort4*>(xr + nb);
    ushort4 ql = *reinterpret_cast<const ushort4*>(xl + nb);
    float xr0 = bf2f(qr.x), xr1 = bf2f(qr.y), xr2 = bf2f(qr.z), xr3 = bf2f(qr.w);
    float l0 = bf2f(ql.x), l1 = bf2f(ql.y), l2 = bf2f(ql.z), l3 = bf2f(ql.w);

    auto grd = [](float p) {
        p += __shfl_xor(p, 1);
        p += __shfl_xor(p, 2);
        p += __shfl_xor(p, 4);
        p += __shfl_xor(p, 8);
        return p;
    };
    auto score4 = [&](float v0, float v1, float v2, float v3) {
        float s0 = v0 + xr0, s1 = v1 + xr1, s2 = v2 + xr2, s3 = v3 + xr3;
        float t0 = fmaxf(s0, LRELU_SLOPE * s0);
        float t1 = fmaxf(s1, LRELU_SLOPE * s1);
        float t2 = fmaxf(s2, LRELU_SLOPE * s2);
        float t3 = fmaxf(s3, LRELU_SLOPE * s3);
        return ((t0 * at0 + t1 * at1) + (t2 * at2 + t3 * at3));
    };

    int beg = rowptr[node], end = rowptr[node + 1];
    int deg = end - beg;
    int lim = end - 1;

    float m = grd(score4(l0, l1, l2, l3));
    float ssum = 1.f;
    float a0 = l0, a1 = l1, a2 = l2, a3 = l3;

    if (deg > 0) {
        int sidx[16];
#pragma unroll
        for (int k = 0; k < 16; k++) sidx[k] = csr_src[min(beg + k, lim)];

        for (int j = 0; j < deg; j += 16) {
            // 16 feature gathers (indices ready from previous iteration) — all in flight
            ushort4 q[16];
#pragma unroll
            for (int k = 0; k < 16; k++)
                q[k] = *reinterpret_cast<const ushort4*>(xl + (size_t)sidx[k] * 64 + c0);
            // prefetch next iteration's indices (independent of q)
            int nidx[16];
#pragma unroll
            for (int k = 0; k < 16; k++) nidx[k] = csr_src[min(beg + j + 16 + k, lim)];

            int rem = deg - j;

            // ---- cluster A: edges j..j+7
            {
                float vv[8][4], e_[8];
#pragma unroll
                for (int k = 0; k < 8; k++) {
                    vv[k][0] = bf2f(q[k].x); vv[k][1] = bf2f(q[k].y);
                    vv[k][2] = bf2f(q[k].z); vv[k][3] = bf2f(q[k].w);
                    e_[k] = grd(score4(vv[k][0], vv[k][1], vv[k][2], vv[k][3]));
                }
#pragma unroll
                for (int k = 1; k < 8; k++) if (k >= rem) e_[k] = -1e30f;
                float mx = fmaxf(fmaxf(fmaxf(e_[0], e_[1]), fmaxf(e_[2], e_[3])),
                                 fmaxf(fmaxf(e_[4], e_[5]), fmaxf(e_[6], e_[7])));
                float mn = fmaxf(m, mx);
                float sc = fast_exp2(m - mn);
                float wgt[8];
#pragma unroll
                for (int k = 0; k < 8; k++) wgt[k] = fast_exp2(e_[k] - mn);
                float sw = ((wgt[0] + wgt[1]) + (wgt[2] + wgt[3])) +
                           ((wgt[4] + wgt[5]) + (wgt[6] + wgt[7]));
                ssum = ssum * sc + sw;
                a0 = a0 * sc + (((wgt[0] * vv[0][0] + wgt[1] * vv[1][0]) + (wgt[2] * vv[2][0] + wgt[3] * vv[3][0])) +
                                ((wgt[4] * vv[4][0] + wgt[5] * vv[5][0]) + (wgt[6] * vv[6][0] + wgt[7] * vv[7][0])));
                a1 = a1 * sc + (((wgt[0] * vv[0][1] + wgt[1] * vv[1][1]) + (wgt[2] * vv[2][1] + wgt[3] * vv[3][1])) +
                                ((wgt[4] * vv[4][1] + wgt[5] * vv[5][1]) + (wgt[6] * vv[6][1] + wgt[7] * vv[7][1])));
                a2 = a2 * sc + (((wgt[0] * vv[0][2] + wgt[1] * vv[1][2]) + (wgt[2] * vv[2][2] + wgt[3] * vv[3][2])) +
                                ((wgt[4] * vv[4][2] + wgt[5] * vv[5][2]) + (wgt[6] * vv[6][2] + wgt[7] * vv[7][2])));
                a3 = a3 * sc + (((wgt[0] * vv[0][3] + wgt[1] * vv[1][3]) + (wgt[2] * vv[2][3] + wgt[3] * vv[3][3])) +
                                ((wgt[4] * vv[4][3] + wgt[5] * vv[5][3]) + (wgt[6] * vv[6][3] + wgt[7] * vv[7][3])));
                m = mn;
            }
            // ---- cluster B: edges j+8..j+15
            if (rem > 8) {
                float vv[8][4], e_[8];
#pragma unroll
                for (int k = 0; k < 8; k++) {
                    vv[k][0] = bf2f(q[8 + k].x); vv[k][1] = bf2f(q[8 + k].y);
                    vv[k][2] = bf2f(q[8 + k].z); vv[k][3] = bf2f(q[8 + k].w);
                    e_[k] = grd(score4(vv[k][0], vv[k][1], vv[k][2], vv[k][3]));
                }
#pragma unroll
                for (int k = 1; k < 8; k++) if (8 + k >= rem) e_[k] = -1e30f;
                float mx = fmaxf(fmaxf(fmaxf(e_[0], e_[1]), fmaxf(e_[2], e_[3])),
                                 fmaxf(fmaxf(e_[4], e_[5]), fmaxf(e_[6], e_[7])));
                float mn = fmaxf(m, mx);
                float sc = fast_exp2(m - mn);
                float wgt[8];
#pragma unroll
                for (int k = 0; k < 8; k++) wgt[k] = fast_exp2(e_[k] - mn);
                float sw = ((wgt[0] + wgt[1]) + (wgt[2] + wgt[3])) +
                           ((wgt[4] + wgt[5]) + (wgt[6] + wgt[7]));
                ssum = ssum * sc + sw;
                a0 = a0 * sc + (((wgt[0] * vv[0][0] + wgt[1] * vv[1][0]) + (wgt[2] * vv[2][0] + wgt[3] * vv[3][0])) +
                                ((wgt[4] * vv[4][0] + wgt[5] * vv[5][0]) + (wgt[6] * vv[6][0] + wgt[7] * vv[7][0])));
                a1 = a1 * sc + (((wgt[0] * vv[0][1] + wgt[1] * vv[1][1]) + (wgt[2] * vv[2][1] + wgt[3] * vv[3][1])) +
                                ((wgt[4] * vv[4][1] + wgt[5] * vv[5][1]) + (wgt[6] * vv[6][1] + wgt[7] * vv[7][1])));
                a2 = a2 * sc + (((wgt[0] * vv[0][2] + wgt[1] * vv[1][2]) + (wgt[2] * vv[2][2] + wgt[3] * vv[3][2])) +
                                ((wgt[4] * vv[4][2] + wgt[5] * vv[5][2]) + (wgt[6] * vv[6][2] + wgt[7] * vv[7][2])));
                a3 = a3 * sc + (((wgt[0] * vv[0][3] + wgt[1] * vv[1][3]) + (wgt[2] * vv[2][3] + wgt[3] * vv[3][3])) +
                                ((wgt[4] * vv[4][3] + wgt[5] * vv[5][3]) + (wgt[6] * vv[6][3] + wgt[7] * vv[7][3])));
                m = mn;
            }

#pragma unroll
            for (int k = 0; k < 16; k++) sidx[k] = nidx[k];
        }
    }

    float rs = 1.f / (ssum + 1e-16f);
    float4 b4 = *reinterpret_cast<const float4*>(bo + c0);
    float o0 = fmaxf(a0 * rs + b4.x, 0.f);
    float o1 = fmaxf(a1 * rs + b4.y, 0.f);
    float o2 = fmaxf(a2 * rs + b4.z, 0.f);
    float o3 = fmaxf(a3 * rs + b4.w, 0.f);
    ushort4 oq;
    oq.x = f2bf(o0); oq.y = f2bf(o1); oq.z = f2bf(o2); oq.w = f2bf(o3);
    *reinterpret_cast<ushort4*>(xout + nb) = oq;
}

// ---------------------------------------------------------------- head
__global__ void k_head(const float* __restrict__ g, const float* __restrict__ pw,
                       const float* __restrict__ pb, const float* __restrict__ cw,
                       const float* __restrict__ cb, float* __restrict__ out) {
    int gb = blockIdx.x;
    int c = threadIdx.x;
    const float* gr = g + gb * 64;
    float a = pb[c];
    const float* pwr = pw + c * 64;
#pragma unroll
    for (int k = 0; k < 64; k++) a += gr[k] * pwr[k];
    a = a > 0.f ? a : 0.f;
    float o0 = wave_sum(a * cw[c]);
    float o1 = wave_sum(a * cw[64 + c]);
    if (c == 0) {
        out[gb * 2 + 0] = o0 + cb[0];
        out[gb * 2 + 1] = o1 + cb[1];
    }
}

// ---------------------------------------------------------------- launcher
extern "C" void kernel_launch(void* const* d_in, const int* in_sizes, int n_in,
                              void* d_out, int out_size, void* d_ws, size_t ws_size,
                              hipStream_t stream) {
    const float* x    = (const float*)d_in[0];
    const int*   ei   = (const int*)d_in[1];
    const int*   bidx = (const int*)d_in[2];
    const float* wl1 = (const float*)d_in[3],  *bl1 = (const float*)d_in[4];
    const float* wr1 = (const float*)d_in[5],  *br1 = (const float*)d_in[6];
    const float* att1 = (const float*)d_in[7], *bo1 = (const float*)d_in[8];
    const float* wl2 = (const float*)d_in[9],  *bl2 = (const float*)d_in[10];
    const float* wr2 = (const float*)d_in[11], *br2 = (const float*)d_in[12];
    const float* att2 = (const float*)d_in[13], *bo2 = (const float*)d_in[14];
    const float* wl3 = (const float*)d_in[15], *bl3 = (const float*)d_in[16];
    const float* wr3 = (const float*)d_in[17], *br3 = (const float*)d_in[18];
    const float* att3 = (const float*)d_in[19], *bo3 = (const float*)d_in[20];
    const float* lw = (const float*)d_in[21], *lb = (const float*)d_in[22];
    const float* pw = (const float*)d_in[23], *pb = (const float*)d_in[24];
    const float* cw = (const float*)d_in[25], *cb = (const float*)d_in[26];
    float* out = (float*)d_out;

    char* wsb = (char*)d_ws;
    size_t off = 0;
    auto alloc = [&](size_t bytes) {
        void* p = wsb + off;
        off = (off + bytes + 255) & ~(size_t)255;
        return p;
    };
    int* rowptr   = (int*)alloc((size_t)(N_NODES + 1) * 4);
    int* bcnt     = (int*)alloc((size_t)NBUCK * 4);
    int* bbase    = (int*)alloc((size_t)NBUCK * 4);
    int* order    = (int*)alloc((size_t)N_NODES * 4);
    int2* stage   = (int2*)alloc((size_t)NBUCK * BCAP * 8);
    int* csr_src  = (int*)alloc((size_t)N_EDGES * 4);
    const int woff[8] = {0, 8192, 16384, 20480, 24576, 28672, 32768, 45056};
    ushort_t* whi = (ushort_t*)alloc((size_t)45056 * 2);
    ushort_t* wlo = (ushort_t*)alloc((size_t)45056 * 2);
    ushort_t* xbf  = (ushort_t*)alloc((size_t)N_NODES * FDIM * 2);
    ushort_t* xl   = (ushort_t*)alloc((size_t)N_NODES * 64 * 2);
    ushort_t* xrr  = (ushort_t*)alloc((size_t)N_NODES * 64 * 2);
    ushort_t* x1b  = (ushort_t*)alloc((size_t)N_NODES * 64 * 2);
    ushort_t* x2b  = (ushort_t*)alloc((size_t)N_NODES * 64 * 2);
    ushort_t* x3b  = (ushort_t*)alloc((size_t)N_NODES * 64 * 2);
    float* g      = (float*)alloc((size_t)NGRAPH * 64 * 4);
    (void)ws_size; (void)in_sizes; (void)n_in; (void)out_size;

    const int* srcp = ei;
    const int* dstp = ei + N_EDGES;

    hipMemsetAsync(bcnt, 0, (size_t)NBUCK * 4, stream);

    k_bucket<<<ABLK, 256, 0, stream>>>(srcp, dstp, bcnt, stage);
    k_bscan<<<1, 256, 0, stream>>>(bcnt, bbase, (float4*)g);
    k_csr<<<NBUCK, 256, 0, stream>>>(bcnt, bbase, stage, rowptr, order, csr_src);

    WSrc ws;
    ws.s[0] = wl1; ws.s[1] = wr1; ws.s[2] = wl2; ws.s[3] = wr2;
    ws.s[4] = wl3; ws.s[5] = wr3; ws.s[6] = lw;
    for (int i = 0; i < 8; i++) ws.off[i] = woff[i];
    k_cvt_w<<<64, 256, 0, stream>>>(ws, whi, wlo);
    k_cvt_x<<<(N_NODES * FDIM / 8 + 255) / 256, 256, 0, stream>>>(x, xbf);

    int gatBlocks = (N_NODES + 15) / 16;

    // layer 1 (K=128, A = xbf)
    k_gemm_dual_mfma<128><<<2 * GEMMB, 256, 0, stream>>>(
        xbf, whi + woff[0], wlo + woff[0], whi + woff[1], wlo + woff[1], bl1, br1, xl, xrr);
    k_gat<<<gatBlocks, 256, 0, stream>>>(xl, xrr, rowptr, csr_src, order, att1, bo1, x1b);
    // layer 2
    k_gemm_dual_mfma<64><<<2 * GEMMB, 256, 0, stream>>>(
        x1b, whi + woff[2], wlo + woff[2], whi + woff[3], wlo + woff[3], bl2, br2, xl, xrr);
    k_gat<<<gatBlocks, 256, 0, stream>>>(xl, xrr, rowptr, csr_src, order, att2, bo2, x2b);
    // layer 3
    k_gemm_dual_mfma<64><<<2 * GEMMB, 256, 0, stream>>>(
        x2b, whi + woff[4], wlo + woff[4], whi + woff[5], wlo + woff[5], bl3, br3, xl, xrr);
    k_gat<<<gatBlocks, 256, 0, stream>>>(xl, xrr, rowptr, csr_src, order, att3, bo3, x3b);

    // fused head GEMM + pool, then classifier
    k_gemm_h_pool<<<GEMMB, 256, 0, stream>>>(x1b, x2b, x3b, whi + woff[6], wlo + woff[6],
                                             lb, bidx, g);
    k_head<<<NGRAPH, 64, 0, stream>>>(g, pw, pb, cw, cb, out);
}

// Round 13
// 253.064 us; speedup vs baseline: 1.0241x; 1.0241x over previous
//
#include <hip/hip_runtime.h>
#include <hip/hip_bf16.h>

#define N_NODES 50000
#define N_EDGES 800000
#define FDIM 128
#define CDIM 64
#define NGRAPH 256
#define LRELU_SLOPE 0.2f
#define NBUCK ((N_NODES + 255) / 256)       // 196 buckets of 256 nodes
#define BCAP 5120                            // stage capacity/bucket
#define ABLK 400                             // pass-A blocks
#define EPB ((N_EDGES + ABLK - 1) / ABLK)    // 2000 edges per pass-A block
#define NDBIN 64                             // degree bins for per-bucket ordering
#define GEMMB ((N_NODES + 63) / 64)          // 782 row-tiles

typedef unsigned short ushort_t;
typedef unsigned int uint_t;
typedef __attribute__((ext_vector_type(8))) short short8v;
typedef __attribute__((ext_vector_type(4))) float float4v;

// ---------------------------------------------------------------- bf16 helpers (RNE)
__device__ __forceinline__ ushort_t f2bf(float f) {
    uint_t u = __float_as_uint(f);
    u += 0x7FFFu + ((u >> 16) & 1u);
    return (ushort_t)(u >> 16);
}
__device__ __forceinline__ float bf2f(ushort_t u) {
    return __uint_as_float(((uint_t)u) << 16);
}

__device__ __forceinline__ float fast_exp2(float x) {
    return __builtin_amdgcn_exp2f(x);
}

__device__ __forceinline__ int wave_incl_scan(int v, int lane) {
#pragma unroll
    for (int off = 1; off < 64; off <<= 1) {
        int t = __shfl_up(v, off);
        if (lane >= off) v += t;
    }
    return v;
}

__device__ __forceinline__ float wave_sum(float v) {
#pragma unroll
    for (int off = 32; off >= 1; off >>= 1) v += __shfl_xor(v, off);
    return v;
}

// ---------------------------------------------------------------- fused conversions:
// blocks 0..63: weights f32 -> hi/lo bf16 ; blocks 64..: x f32 -> bf16
struct WSrc {
    const float* s[7];
    int off[8];
};
__global__ void k_cvt(WSrc ws, ushort_t* __restrict__ hi, ushort_t* __restrict__ lo,
                      const float* __restrict__ x, ushort_t* __restrict__ xb) {
    if (blockIdx.x < 64) {
        int gid = blockIdx.x * 256 + threadIdx.x;
        int stride = 64 * 256;
#pragma unroll
        for (int mi = 0; mi < 7; mi++) {
            int n = ws.off[mi + 1] - ws.off[mi];
            const float* s = ws.s[mi];
            ushort_t* h = hi + ws.off[mi];
            ushort_t* l = lo + ws.off[mi];
            for (int i = gid; i < n; i += stride) {
                float f = s[i];
                ushort_t hb = f2bf(f);
                h[i] = hb;
                l[i] = f2bf(f - bf2f(hb));
            }
        }
    } else {
        int i = (blockIdx.x - 64) * 256 + threadIdx.x;
        const int TOT = N_NODES * FDIM / 8;
        if (i >= TOT) return;
        const float* p = x + (size_t)i * 8;
        float4 a = *reinterpret_cast<const float4*>(p);
        float4 b = *reinterpret_cast<const float4*>(p + 4);
        short8v o;
        o[0] = (short)f2bf(a.x); o[1] = (short)f2bf(a.y);
        o[2] = (short)f2bf(a.z); o[3] = (short)f2bf(a.w);
        o[4] = (short)f2bf(b.x); o[5] = (short)f2bf(b.y);
        o[6] = (short)f2bf(b.z); o[7] = (short)f2bf(b.w);
        *reinterpret_cast<short8v*>(xb + (size_t)i * 8) = o;
    }
}

// ---------------------------------------------------------------- CSR build
__global__ void k_bucket(const int* __restrict__ src, const int* __restrict__ dst,
                         int* __restrict__ bcnt, int2* __restrict__ stage) {
    __shared__ int lhist[NBUCK];
    __shared__ int lbase[NBUCK];
    __shared__ int lcur[NBUCK];
    int tid = threadIdx.x;
    int e0 = blockIdx.x * EPB;
    int e1 = min(e0 + EPB, N_EDGES);
    int es[8], ed[8];
    int myn = 0;
#pragma unroll
    for (int k = 0; k < 8; k++) {
        int e = e0 + tid + k * 256;
        if (e < e1) { es[k] = src[e]; ed[k] = dst[e]; myn = k + 1; }
    }
    for (int t = tid; t < NBUCK; t += 256) { lhist[t] = 0; lcur[t] = 0; }
    __syncthreads();
#pragma unroll
    for (int k = 0; k < 8; k++)
        if (k < myn) atomicAdd(&lhist[ed[k] >> 8], 1);
    __syncthreads();
    for (int t = tid; t < NBUCK; t += 256)
        lbase[t] = lhist[t] ? atomicAdd(&bcnt[t], lhist[t]) : 0;
    __syncthreads();
#pragma unroll
    for (int k = 0; k < 8; k++) {
        if (k < myn) {
            int b = ed[k] >> 8;
            int loff = atomicAdd(&lcur[b], 1);
            int pos = lbase[b] + loff;
            if (pos < BCAP) stage[(size_t)b * BCAP + pos] = make_int2(es[k], ed[k]);
        }
    }
}

// exclusive scan of bucket counts (one block) + zero the pool buffer g
__global__ void k_bscan(const int* __restrict__ bcnt, int* __restrict__ bbase,
                        float4* __restrict__ g4) {
    __shared__ int wsum[4];
    int tid = threadIdx.x;
    int lane = tid & 63, w = tid >> 6;
    int v = (tid < NBUCK) ? bcnt[tid] : 0;
    int incl = wave_incl_scan(v, lane);
    if (lane == 63) wsum[w] = incl;
    __syncthreads();
    if (tid == 0) {
        int s = 0;
#pragma unroll
        for (int k = 0; k < 4; k++) { int t = wsum[k]; wsum[k] = s; s += t; }
    }
    __syncthreads();
    if (tid < NBUCK) bbase[tid] = incl - v + wsum[w];
    const int G4 = NGRAPH * 64 / 4;
    for (int i = tid; i < G4; i += 256) g4[i] = make_float4(0.f, 0.f, 0.f, 0.f);
}

// fused per-bucket: node hist + rowptr + per-bucket degree-sort order + scatter
__global__ void k_csr(const int* __restrict__ bcnt, const int* __restrict__ bbase,
                      const int2* __restrict__ stage, int* __restrict__ rowptr,
                      int* __restrict__ order, int* __restrict__ csr_src) {
    __shared__ int lcnt[256];
    __shared__ int lcur[256];
    __shared__ int dh[NDBIN];
    __shared__ int dbase[NDBIN];
    __shared__ int wsum[4];
    int b = blockIdx.x;
    int tid = threadIdx.x;
    int lane = tid & 63, w = tid >> 6;
    lcnt[tid] = 0;
    if (tid < NDBIN) dh[tid] = 0;
    __syncthreads();
    int n = min(bcnt[b], BCAP);
    const int2* sp = stage + (size_t)b * BCAP;
    for (int i = tid; i < n; i += 256)
        atomicAdd(&lcnt[sp[i].y & 255], 1);
    __syncthreads();
    int v = lcnt[tid];
    int incl = wave_incl_scan(v, lane);
    if (lane == 63) wsum[w] = incl;
    __syncthreads();
    if (tid == 0) {
        int s = 0;
#pragma unroll
        for (int k = 0; k < 4; k++) { int t = wsum[k]; wsum[k] = s; s += t; }
    }
    __syncthreads();
    int excl = incl - v + wsum[w];
    int bb = bbase[b];
    int node = (b << 8) + tid;
    bool okn = node < N_NODES;
    int dg = min(v, NDBIN - 1);
    if (okn) {
        rowptr[node] = bb + excl;
        atomicAdd(&dh[dg], 1);
    }
    lcur[tid] = excl;
    if (b == 0 && tid == 0) rowptr[N_NODES] = N_EDGES;
    __syncthreads();
    if (tid < NDBIN) {
        int dv = dh[tid];
        int din = wave_incl_scan(dv, tid);
        dbase[tid] = din - dv;
    }
    __syncthreads();
    if (okn) {
        int r = atomicAdd(&dbase[dg], 1);
        order[(b << 8) + r] = node;
    }
    for (int i = tid; i < n; i += 256) {
        int2 sd = sp[i];
        int pos = atomicAdd(&lcur[sd.y & 255], 1);
        csr_src[bb + pos] = sd.x;
    }
}

// ---------------------------------------------------------------- projection via MFMA
template <int K>
__global__ void k_gemm_dual_mfma(const ushort_t* __restrict__ xa,
                                 const ushort_t* __restrict__ wlh, const ushort_t* __restrict__ wll,
                                 const ushort_t* __restrict__ wrh, const ushort_t* __restrict__ wrl,
                                 const float* __restrict__ bl, const float* __restrict__ br,
                                 ushort_t* __restrict__ xl, ushort_t* __restrict__ xr) {
    int tid = threadIdx.x;
    int wv = tid >> 6, lane = tid & 63;
    bool rhalf = blockIdx.x >= GEMMB;
    int blk = rhalf ? blockIdx.x - GEMMB : blockIdx.x;
    int m0 = blk * 64 + wv * 16;
    if (m0 >= N_NODES) return;
    int arow = min(m0 + (lane & 15), N_NODES - 1);
    int koff = (lane >> 4) * 8;
    int wrow = lane & 15;
    const ushort_t* bh  = rhalf ? wrh : wlh;
    const ushort_t* blo = rhalf ? wrl : wll;
    const float* bias   = rhalf ? br : bl;
    ushort_t* outp      = rhalf ? xr : xl;

    short8v afrag[K / 32];
#pragma unroll
    for (int kk = 0; kk < K / 32; kk++)
        afrag[kk] = *reinterpret_cast<const short8v*>(xa + (size_t)arow * K + kk * 32 + koff);

    float4v acc[4];
#pragma unroll
    for (int f = 0; f < 4; f++) acc[f] = (float4v)(0.f);

#pragma unroll
    for (int kk = 0; kk < K / 32; kk++) {
#pragma unroll
        for (int f = 0; f < 4; f++) {
            size_t boff = (size_t)(f * 16 + wrow) * K + kk * 32 + koff;
            short8v bfh = *reinterpret_cast<const short8v*>(bh + boff);
            short8v bfl = *reinterpret_cast<const short8v*>(blo + boff);
            acc[f] = __builtin_amdgcn_mfma_f32_16x16x32_bf16(afrag[kk], bfh, acc[f], 0, 0, 0);
            acc[f] = __builtin_amdgcn_mfma_f32_16x16x32_bf16(afrag[kk], bfl, acc[f], 0, 0, 0);
        }
    }

    int r0 = m0 + (lane >> 4) * 4;
#pragma unroll
    for (int f = 0; f < 4; f++) {
        int col = f * 16 + (lane & 15);
        float bv = bias[col];
#pragma unroll
        for (int j = 0; j < 4; j++) {
            int row = r0 + j;
            if (row < N_NODES) outp[(size_t)row * 64 + col] = f2bf(acc[f][j] + bv);
        }
    }
}

// ---------------------------------------------------------------- fused: h = relu(concat@W.T+b) -> global_add_pool
__global__ void k_gemm_h_pool(const ushort_t* __restrict__ x1, const ushort_t* __restrict__ x2,
                              const ushort_t* __restrict__ x3,
                              const ushort_t* __restrict__ whi, const ushort_t* __restrict__ wlo,
                              const float* __restrict__ b, const int* __restrict__ batch,
                              float* __restrict__ g) {
    __shared__ float ht[64][65];
    int tid = threadIdx.x;
    int wv = tid >> 6, lane = tid & 63;
    int m0 = blockIdx.x * 64 + wv * 16;
    bool wactive = m0 < N_NODES;

    if (wactive) {
        int arow = min(m0 + (lane & 15), N_NODES - 1);
        int koff = (lane >> 4) * 8;
        int wrow = lane & 15;
        float4v acc[4];
#pragma unroll
        for (int f = 0; f < 4; f++) acc[f] = (float4v)(0.f);
#pragma unroll
        for (int ks = 0; ks < 6; ks++) {
            int k0 = ks * 32;
            const ushort_t* srcp = (ks < 2) ? x1 : (ks < 4 ? x2 : x3);
            int kc = k0 & 63;
            short8v afrag = *reinterpret_cast<const short8v*>(srcp + (size_t)arow * 64 + kc + koff);
#pragma unroll
            for (int f = 0; f < 4; f++) {
                size_t boff = (size_t)(f * 16 + wrow) * 192 + k0 + koff;
                short8v bfh = *reinterpret_cast<const short8v*>(whi + boff);
                short8v bfl = *reinterpret_cast<const short8v*>(wlo + boff);
                acc[f] = __builtin_amdgcn_mfma_f32_16x16x32_bf16(afrag, bfh, acc[f], 0, 0, 0);
                acc[f] = __builtin_amdgcn_mfma_f32_16x16x32_bf16(afrag, bfl, acc[f], 0, 0, 0);
            }
        }
        int r0 = wv * 16 + (lane >> 4) * 4;
#pragma unroll
        for (int f = 0; f < 4; f++) {
            int col = f * 16 + (lane & 15);
            float bias = b[col];
#pragma unroll
            for (int j = 0; j < 4; j++) {
                float o = acc[f][j] + bias;
                ht[r0 + j][col] = o > 0.f ? o : 0.f;
            }
        }
    }
    __syncthreads();

    int c = tid & 63, rr = tid >> 6;
    int blkbase = blockIdx.x * 64;
    float acc = 0.f;
    int cur = -1;
    for (int r = rr; r < 64; r += 4) {
        int node = blkbase + r;
        if (node >= N_NODES) break;
        int bb = batch[node];
        if (bb != cur) {
            if (cur >= 0) atomicAdd(&g[cur * 64 + c], acc);
            cur = bb;
            acc = 0.f;
        }
        acc += ht[r][c];
    }
    if (cur >= 0) atomicAdd(&g[cur * 64 + c], acc);
}

// ---------------------------------------------------------------- GATv2 aggregate
// 4 nodes/wave (16 lanes, 4ch/lane), degree-ordered; 8-edge unrolled online softmax (log2 domain)
// (round-11 body — best measured variant)
__global__ void k_gat(const ushort_t* __restrict__ xl, const ushort_t* __restrict__ xr,
                      const int* __restrict__ rowptr, const int* __restrict__ csr_src,
                      const int* __restrict__ order,
                      const float* __restrict__ att, const float* __restrict__ bo,
                      ushort_t* __restrict__ xout) {
    int tid = threadIdx.x;
    int wv = tid >> 6, lane = tid & 63;
    int gl = lane & 15;
    int slot = blockIdx.x * 16 + wv * 4 + (lane >> 4);
    if (slot >= N_NODES) return;
    int node = order[slot];
    const float LOG2E = 1.44269504f;
    int c0 = gl * 4;
    float4 a4 = *reinterpret_cast<const float4*>(att + c0);
    float at0 = a4.x * LOG2E, at1 = a4.y * LOG2E, at2 = a4.z * LOG2E, at3 = a4.w * LOG2E;
    size_t nb = (size_t)node * 64 + c0;
    ushort4 qr = *reinterpret_cast<const ushort4*>(xr + nb);
    ushort4 ql = *reinterpret_cast<const ushort4*>(xl + nb);
    float xr0 = bf2f(qr.x), xr1 = bf2f(qr.y), xr2 = bf2f(qr.z), xr3 = bf2f(qr.w);
    float l0 = bf2f(ql.x), l1 = bf2f(ql.y), l2 = bf2f(ql.z), l3 = bf2f(ql.w);

    auto grd = [](float p) {
        p += __shfl_xor(p, 1);
        p += __shfl_xor(p, 2);
        p += __shfl_xor(p, 4);
        p += __shfl_xor(p, 8);
        return p;
    };
    auto score4 = [&](float v0, float v1, float v2, float v3) {
        float s0 = v0 + xr0, s1 = v1 + xr1, s2 = v2 + xr2, s3 = v3 + xr3;
        float t0 = fmaxf(s0, LRELU_SLOPE * s0);
        float t1 = fmaxf(s1, LRELU_SLOPE * s1);
        float t2 = fmaxf(s2, LRELU_SLOPE * s2);
        float t3 = fmaxf(s3, LRELU_SLOPE * s3);
        return ((t0 * at0 + t1 * at1) + (t2 * at2 + t3 * at3));
    };

    int beg = rowptr[node], end = rowptr[node + 1];
    int deg = end - beg;
    int lim = end - 1;

    float m = grd(score4(l0, l1, l2, l3));
    float ssum = 1.f;
    float a0 = l0, a1 = l1, a2 = l2, a3 = l3;

    for (int j = 0; j < deg; j += 8) {
        int base = beg + j;
        int i0 = base;
        int i1 = min(base + 1, lim), i2 = min(base + 2, lim), i3 = min(base + 3, lim);
        int i4 = min(base + 4, lim), i5 = min(base + 5, lim);
        int i6 = min(base + 6, lim), i7 = min(base + 7, lim);
        int s0 = csr_src[i0], s1 = csr_src[i1], s2 = csr_src[i2], s3 = csr_src[i3];
        int s4 = csr_src[i4], s5 = csr_src[i5], s6 = csr_src[i6], s7 = csr_src[i7];
        ushort4 q0 = *reinterpret_cast<const ushort4*>(xl + (size_t)s0 * 64 + c0);
        ushort4 q1 = *reinterpret_cast<const ushort4*>(xl + (size_t)s1 * 64 + c0);
        ushort4 q2 = *reinterpret_cast<const ushort4*>(xl + (size_t)s2 * 64 + c0);
        ushort4 q3 = *reinterpret_cast<const ushort4*>(xl + (size_t)s3 * 64 + c0);
        ushort4 q4 = *reinterpret_cast<const ushort4*>(xl + (size_t)s4 * 64 + c0);
        ushort4 q5 = *reinterpret_cast<const ushort4*>(xl + (size_t)s5 * 64 + c0);
        ushort4 q6 = *reinterpret_cast<const ushort4*>(xl + (size_t)s6 * 64 + c0);
        ushort4 q7 = *reinterpret_cast<const ushort4*>(xl + (size_t)s7 * 64 + c0);
        float v00 = bf2f(q0.x), v01 = bf2f(q0.y), v02 = bf2f(q0.z), v03 = bf2f(q0.w);
        float v10 = bf2f(q1.x), v11 = bf2f(q1.y), v12 = bf2f(q1.z), v13 = bf2f(q1.w);
        float v20 = bf2f(q2.x), v21 = bf2f(q2.y), v22 = bf2f(q2.z), v23 = bf2f(q2.w);
        float v30 = bf2f(q3.x), v31 = bf2f(q3.y), v32 = bf2f(q3.z), v33 = bf2f(q3.w);
        float v40 = bf2f(q4.x), v41 = bf2f(q4.y), v42 = bf2f(q4.z), v43 = bf2f(q4.w);
        float v50 = bf2f(q5.x), v51 = bf2f(q5.y), v52 = bf2f(q5.z), v53 = bf2f(q5.w);
        float v60 = bf2f(q6.x), v61 = bf2f(q6.y), v62 = bf2f(q6.z), v63 = bf2f(q6.w);
        float v70 = bf2f(q7.x), v71 = bf2f(q7.y), v72 = bf2f(q7.z), v73 = bf2f(q7.w);
        float e0 = grd(score4(v00, v01, v02, v03));
        float e1 = grd(score4(v10, v11, v12, v13));
        float e2 = grd(score4(v20, v21, v22, v23));
        float e3 = grd(score4(v30, v31, v32, v33));
        float e4 = grd(score4(v40, v41, v42, v43));
        float e5 = grd(score4(v50, v51, v52, v53));
        float e6 = grd(score4(v60, v61, v62, v63));
        float e7 = grd(score4(v70, v71, v72, v73));
        int rem = deg - j;
        if (rem < 8) {
            e1 = (rem > 1) ? e1 : -1e30f;
            e2 = (rem > 2) ? e2 : -1e30f;
            e3 = (rem > 3) ? e3 : -1e30f;
            e4 = (rem > 4) ? e4 : -1e30f;
            e5 = (rem > 5) ? e5 : -1e30f;
            e6 = (rem > 6) ? e6 : -1e30f;
            e7 = (rem > 7) ? e7 : -1e30f;
        }
        float mx = fmaxf(fmaxf(fmaxf(e0, e1), fmaxf(e2, e3)),
                         fmaxf(fmaxf(e4, e5), fmaxf(e6, e7)));
        float mn = fmaxf(m, mx);
        float sc = fast_exp2(m - mn);
        float w0 = fast_exp2(e0 - mn), w1 = fast_exp2(e1 - mn);
        float w2 = fast_exp2(e2 - mn), w3 = fast_exp2(e3 - mn);
        float w4 = fast_exp2(e4 - mn), w5 = fast_exp2(e5 - mn);
        float w6 = fast_exp2(e6 - mn), w7 = fast_exp2(e7 - mn);
        ssum = ssum * sc + (((w0 + w1) + (w2 + w3)) + ((w4 + w5) + (w6 + w7)));
        a0 = a0 * sc + (((w0 * v00 + w1 * v10) + (w2 * v20 + w3 * v30)) +
                        ((w4 * v40 + w5 * v50) + (w6 * v60 + w7 * v70)));
        a1 = a1 * sc + (((w0 * v01 + w1 * v11) + (w2 * v21 + w3 * v31)) +
                        ((w4 * v41 + w5 * v51) + (w6 * v61 + w7 * v71)));
        a2 = a2 * sc + (((w0 * v02 + w1 * v12) + (w2 * v22 + w3 * v32)) +
                        ((w4 * v42 + w5 * v52) + (w6 * v62 + w7 * v72)));
        a3 = a3 * sc + (((w0 * v03 + w1 * v13) + (w2 * v23 + w3 * v33)) +
                        ((w4 * v43 + w5 * v53) + (w6 * v63 + w7 * v73)));
        m = mn;
    }

    float rs = 1.f / (ssum + 1e-16f);
    float4 b4 = *reinterpret_cast<const float4*>(bo + c0);
    float o0 = fmaxf(a0 * rs + b4.x, 0.f);
    float o1 = fmaxf(a1 * rs + b4.y, 0.f);
    float o2 = fmaxf(a2 * rs + b4.z, 0.f);
    float o3 = fmaxf(a3 * rs + b4.w, 0.f);
    ushort4 oq;
    oq.x = f2bf(o0); oq.y = f2bf(o1); oq.z = f2bf(o2); oq.w = f2bf(o3);
    *reinterpret_cast<ushort4*>(xout + nb) = oq;
}

// ---------------------------------------------------------------- head
__global__ void k_head(const float* __restrict__ g, const float* __restrict__ pw,
                       const float* __restrict__ pb, const float* __restrict__ cw,
                       const float* __restrict__ cb, float* __restrict__ out) {
    int gb = blockIdx.x;
    int c = threadIdx.x;
    const float* gr = g + gb * 64;
    float a = pb[c];
    const float* pwr = pw + c * 64;
#pragma unroll
    for (int k = 0; k < 64; k++) a += gr[k] * pwr[k];
    a = a > 0.f ? a : 0.f;
    float o0 = wave_sum(a * cw[c]);
    float o1 = wave_sum(a * cw[64 + c]);
    if (c == 0) {
        out[gb * 2 + 0] = o0 + cb[0];
        out[gb * 2 + 1] = o1 + cb[1];
    }
}

// ---------------------------------------------------------------- launcher
extern "C" void kernel_launch(void* const* d_in, const int* in_sizes, int n_in,
                              void* d_out, int out_size, void* d_ws, size_t ws_size,
                              hipStream_t stream) {
    const float* x    = (const float*)d_in[0];
    const int*   ei   = (const int*)d_in[1];
    const int*   bidx = (const int*)d_in[2];
    const float* wl1 = (const float*)d_in[3],  *bl1 = (const float*)d_in[4];
    const float* wr1 = (const float*)d_in[5],  *br1 = (const float*)d_in[6];
    const float* att1 = (const float*)d_in[7], *bo1 = (const float*)d_in[8];
    const float* wl2 = (const float*)d_in[9],  *bl2 = (const float*)d_in[10];
    const float* wr2 = (const float*)d_in[11], *br2 = (const float*)d_in[12];
    const float* att2 = (const float*)d_in[13], *bo2 = (const float*)d_in[14];
    const float* wl3 = (const float*)d_in[15], *bl3 = (const float*)d_in[16];
    const float* wr3 = (const float*)d_in[17], *br3 = (const float*)d_in[18];
    const float* att3 = (const float*)d_in[19], *bo3 = (const float*)d_in[20];
    const float* lw = (const float*)d_in[21], *lb = (const float*)d_in[22];
    const float* pw = (const float*)d_in[23], *pb = (const float*)d_in[24];
    const float* cw = (const float*)d_in[25], *cb = (const float*)d_in[26];
    float* out = (float*)d_out;

    char* wsb = (char*)d_ws;
    size_t off = 0;
    auto alloc = [&](size_t bytes) {
        void* p = wsb + off;
        off = (off + bytes + 255) & ~(size_t)255;
        return p;
    };
    int* rowptr   = (int*)alloc((size_t)(N_NODES + 1) * 4);
    int* bcnt     = (int*)alloc((size_t)NBUCK * 4);
    int* bbase    = (int*)alloc((size_t)NBUCK * 4);
    int* order    = (int*)alloc((size_t)N_NODES * 4);
    int2* stage   = (int2*)alloc((size_t)NBUCK * BCAP * 8);
    int* csr_src  = (int*)alloc((size_t)N_EDGES * 4);
    const int woff[8] = {0, 8192, 16384, 20480, 24576, 28672, 32768, 45056};
    ushort_t* whi = (ushort_t*)alloc((size_t)45056 * 2);
    ushort_t* wlo = (ushort_t*)alloc((size_t)45056 * 2);
    ushort_t* xbf  = (ushort_t*)alloc((size_t)N_NODES * FDIM * 2);
    ushort_t* xl   = (ushort_t*)alloc((size_t)N_NODES * 64 * 2);
    ushort_t* xrr  = (ushort_t*)alloc((size_t)N_NODES * 64 * 2);
    ushort_t* x1b  = (ushort_t*)alloc((size_t)N_NODES * 64 * 2);
    ushort_t* x2b  = (ushort_t*)alloc((size_t)N_NODES * 64 * 2);
    ushort_t* x3b  = (ushort_t*)alloc((size_t)N_NODES * 64 * 2);
    float* g      = (float*)alloc((size_t)NGRAPH * 64 * 4);
    (void)ws_size; (void)in_sizes; (void)n_in; (void)out_size;

    const int* srcp = ei;
    const int* dstp = ei + N_EDGES;

    hipMemsetAsync(bcnt, 0, (size_t)NBUCK * 4, stream);

    k_bucket<<<ABLK, 256, 0, stream>>>(srcp, dstp, bcnt, stage);
    k_bscan<<<1, 256, 0, stream>>>(bcnt, bbase, (float4*)g);
    k_csr<<<NBUCK, 256, 0, stream>>>(bcnt, bbase, stage, rowptr, order, csr_src);

    WSrc ws;
    ws.s[0] = wl1; ws.s[1] = wr1; ws.s[2] = wl2; ws.s[3] = wr2;
    ws.s[4] = wl3; ws.s[5] = wr3; ws.s[6] = lw;
    for (int i = 0; i < 8; i++) ws.off[i] = woff[i];
    k_cvt<<<64 + (N_NODES * FDIM / 8 + 255) / 256, 256, 0, stream>>>(ws, whi, wlo, x, xbf);

    int gatBlocks = (N_NODES + 15) / 16;

    // layer 1 (K=128, A = xbf)
    k_gemm_dual_mfma<128><<<2 * GEMMB, 256, 0, stream>>>(
        xbf, whi + woff[0], wlo + woff[0], whi + woff[1], wlo + woff[1], bl1, br1, xl, xrr);
    k_gat<<<gatBlocks, 256, 0, stream>>>(xl, xrr, rowptr, csr_src, order, att1, bo1, x1b);
    // layer 2
    k_gemm_dual_mfma<64><<<2 * GEMMB, 256, 0, stream>>>(
        x1b, whi + woff[2], wlo + woff[2], whi + woff[3], wlo + woff[3], bl2, br2, xl, xrr);
    k_gat<<<gatBlocks, 256, 0, stream>>>(xl, xrr, rowptr, csr_src, order, att2, bo2, x2b);
    // layer 3
    k_gemm_dual_mfma<64><<<2 * GEMMB, 256, 0, stream>>>(
        x2b, whi + woff[4], wlo + woff[4], whi + woff[5], wlo + woff[5], bl3, br3, xl, xrr);
    k_gat<<<gatBlocks, 256, 0, stream>>>(xl, xrr, rowptr, csr_src, order, att3, bo3, x3b);

    // fused head GEMM + pool, then classifier
    k_gemm_h_pool<<<GEMMB, 256, 0, stream>>>(x1b, x2b, x3b, whi + woff[6], wlo + woff[6],
                                             lb, bidx, g);
    k_head<<<NGRAPH, 64, 0, stream>>>(g, pw, pb, cw, cb, out);
}